// Round 5
// baseline (258.057 us; speedup 1.0000x reference)
//
#include <hip/hip_runtime.h>
#include <float.h>
#include <stdint.h>

// Problem constants: B=64, H=W=32, C=256, D=H*W=1024, K=1024
#define B_   64
#define C_   256
#define D_   1024
#define K_   1024
#define M_   16384
#define NX_  16777216          // B*D*C = M*D
#define DISC_OFF NX_
#define LOSS_OFF (NX_ + M_)

typedef _Float16 h8 __attribute__((ext_vector_type(8)));
typedef float    f4 __attribute__((ext_vector_type(4)));

// Power-of-2 split scales (exact). acc = 2^20 * dot.
#define XSCALE 512.0f
#define ESCALE 2048.0f
#define DOT_UNSCALE_2 (2.0f / 1048576.0f)

// d_ws layout (float offsets).
#define WS_EH  0          // 1M fp16 = 524288 floats
#define WS_EL  524288
#define WS_CN  1048576    // 1024
#define WS_PCN 1049600    // 128*1024 = 131072
#define WS_PV  1180672    // 16384*4 = 65536
#define WS_PI  1246208    // 16384*4 = 65536

__device__ __forceinline__ void async16(const _Float16* g, _Float16* l) {
    __builtin_amdgcn_global_load_lds(
        (const __attribute__((address_space(1))) unsigned int*)g,
        (__attribute__((address_space(3))) unsigned int*)l, 16, 0, 0);
}

// ---------------------------------------------------------------------------
// Fused split kernel, VECTORIZED (16B/lane loads, G13).
// Blocks [0,128): E -> fragment-tiled fp16 hi/lo planes + colnorm partials.
//   block = one k-octet o; thread = 4 consecutive n. Wave load = 1KB contig.
// Blocks [128,2176): x -> same layout. thread = 4 consecutive c, one octet.
// Fragment layout identical to previous rounds (bit-exact planes).
// ---------------------------------------------------------------------------
__global__ __launch_bounds__(256) void split_kernel(const float* __restrict__ x,
                                                    const float* __restrict__ E,
                                                    _Float16* __restrict__ Xh,
                                                    _Float16* __restrict__ Xl,
                                                    _Float16* __restrict__ Eh,
                                                    _Float16* __restrict__ El,
                                                    float* __restrict__ pcn) {
    const int bid = blockIdx.x;
    const int t   = threadIdx.x;
    if (bid < 128) {
        // ---- E split + colnorm partials ----
        const int o  = bid;            // k-octet [0,128)
        const int d0 = o * 8;
        const int n0 = t * 4;          // 4 consecutive columns
        float4 row[8];
        #pragma unroll
        for (int i = 0; i < 8; ++i)
            row[i] = *(const float4*)(E + (size_t)(d0 + i) * K_ + n0);
        float s0 = 0.f, s1 = 0.f, s2 = 0.f, s3 = 0.f;
        h8 hh[4], ll[4];
        #pragma unroll
        for (int i = 0; i < 8; ++i) {
            const float* rp = (const float*)&row[i];
            #pragma unroll
            for (int j = 0; j < 4; ++j) {
                const float v  = rp[j];
                const float vs = v * ESCALE;
                const _Float16 h = (_Float16)vs;
                hh[j][i] = h;
                ll[j][i] = (_Float16)(vs - (float)h);
            }
            s0 = fmaf(rp[0], rp[0], s0);
            s1 = fmaf(rp[1], rp[1], s1);
            s2 = fmaf(rp[2], rp[2], s2);
            s3 = fmaf(rp[3], rp[3], s3);
        }
        float4 sv; sv.x = s0; sv.y = s1; sv.z = s2; sv.w = s3;
        *(float4*)(pcn + o * K_ + n0) = sv;
        const int nt    = n0 >> 4;
        const int kt    = o >> 2;
        const int lane0 = (n0 & 15) + (o & 3) * 16;
        const size_t base = ((size_t)(nt * 32 + kt) * 64 + lane0) * 8;
        #pragma unroll
        for (int j = 0; j < 4; ++j) {
            *(h8*)(Eh + base + (size_t)j * 8) = hh[j];
            *(h8*)(El + base + (size_t)j * 8) = ll[j];
        }
    } else {
        // ---- x split ----
        const int tid = (bid - 128) * 256 + t;   // [0, 524288)
        const int o   = tid >> 12;               // k-octet [0,128)
        const int q   = tid & 4095;
        const int b   = q >> 6;                  // [0,64)
        const int c0  = (q & 63) * 4;            // 4 consecutive channels
        const int d0  = o * 8;
        const float* xp = x + ((size_t)(b * 1024 + d0) * 256) + c0;
        float4 row[8];
        #pragma unroll
        for (int i = 0; i < 8; ++i)
            row[i] = *(const float4*)(xp + (size_t)i * 256);
        h8 hh[4], ll[4];
        #pragma unroll
        for (int i = 0; i < 8; ++i) {
            const float* rp = (const float*)&row[i];
            #pragma unroll
            for (int j = 0; j < 4; ++j) {
                const float vs = rp[j] * XSCALE;
                const _Float16 h = (_Float16)vs;
                hh[j][i] = h;
                ll[j][i] = (_Float16)(vs - (float)h);
            }
        }
        const int m     = b * 256 + c0;
        const int mt    = m >> 4;
        const int kt    = o >> 2;
        const int lane0 = (m & 15) + (o & 3) * 16;
        const size_t base = ((size_t)(mt * 32 + kt) * 64 + lane0) * 8;
        #pragma unroll
        for (int j = 0; j < 4; ++j) {
            *(h8*)(Xh + base + (size_t)j * 8) = hh[j];
            *(h8*)(Xl + base + (size_t)j * 8) = ll[j];
        }
    }
}

// colnorm: sum the 128 partials per column; zero the loss slot.
__global__ __launch_bounds__(256) void colnorm2_kernel(const float* __restrict__ pcn,
                                                       float* __restrict__ cn,
                                                       float* __restrict__ loss_slot) {
    __shared__ float sp[4][64];
    const int t    = threadIdx.x;
    const int col  = blockIdx.x * 64 + (t & 63);
    const int part = t >> 6;
    float s = 0.f;
    #pragma unroll 8
    for (int i = 0; i < 32; ++i) s += pcn[(part * 32 + i) * K_ + col];
    sp[part][t & 63] = s;
    __syncthreads();
    if (t < 64) cn[col] = (sp[0][t] + sp[1][t]) + (sp[2][t] + sp[3][t]);
    if (blockIdx.x == 0 && t == 0) *loss_slot = 0.0f;
}

// ---------------------------------------------------------------------------
// Split-fp16 MFMA distance GEMM + per-block argmin.  (R0-exact: best measured
// 99.8 us / 45.6% MfmaUtil; structural rewrites R1-R4 all regressed.)
// 128x256 tile, 512 threads (8 waves, each 64x64), BK=32, double-buffered LDS
// (2 x 48 KB) with cross-step async prefetch: one barrier per k-step; loads
// for step s+1 issue before compute of step s -> latency hidden by MFMA.
// Grid 512 = 128 rt x 4 ct (consecutive blocks share rt -> A via L3).
// ---------------------------------------------------------------------------
__global__ __launch_bounds__(512, 2) void gemm_argmin_kernel(
        const _Float16* __restrict__ Xh, const _Float16* __restrict__ Xl,
        const _Float16* __restrict__ Eh, const _Float16* __restrict__ El,
        const float* __restrict__ cn,
        float* __restrict__ pV, int* __restrict__ pI) {
    extern __shared__ _Float16 smem[];
    // A buffers: [2][plane*8+mt][512]   (8192 fp16 each)
    // B buffers: [2][plane*16+nt][512]  (16384 fp16 each)
    _Float16* Ab0 = smem;
    _Float16* Ab1 = smem + 8192;
    _Float16* Bb0 = smem + 16384;
    _Float16* Bb1 = smem + 32768;
    float* cV = (float*)(smem + 49152);   // [128][4]
    int*   cI = (int*)(cV + 512);         // [128][4]

    const int t    = threadIdx.x;
    const int rt   = blockIdx.x >> 2;     // 0..127
    const int ct   = blockIdx.x & 3;      // 0..3
    const int wave = t >> 6, lane = t & 63;
    const int lo16 = lane & 15, hi4 = lane >> 4;
    const int mq   = (wave & 1) * 64;
    const int nq   = (wave >> 1) * 64;    // 0,64,128,192
    const int mt0  = rt * 8, nt0 = ct * 16;
    const int n0g  = ct * 256;

    // 48 async chunk-loads per k-step, 6 per wave.
    // id 0..15: A (plane=id>>3, mt=id&7); id 16..47: B (plane=(id-16)>>4, nt=(id-16)&15)
    const _Float16* src[6];
    _Float16* dst0[6];
    _Float16* dst1[6];
    #pragma unroll
    for (int i = 0; i < 6; ++i) {
        const int id = wave * 6 + i;
        if (id < 16) {
            const int plane = id >> 3, mt = id & 7;
            src[i]  = (plane ? Xl : Xh) + ((size_t)(mt0 + mt) * 32) * 512 + lane * 8;
            dst0[i] = Ab0 + (plane * 8 + mt) * 512 + lane * 8;
            dst1[i] = Ab1 + (plane * 8 + mt) * 512 + lane * 8;
        } else {
            const int q = id - 16;
            const int plane = q >> 4, nt = q & 15;
            src[i]  = (plane ? El : Eh) + ((size_t)(nt0 + nt) * 32) * 512 + lane * 8;
            dst0[i] = Bb0 + (plane * 16 + nt) * 512 + lane * 8;
            dst1[i] = Bb1 + (plane * 16 + nt) * 512 + lane * 8;
        }
    }

    f4 acc[4][4];
    const f4 zero = {0.f, 0.f, 0.f, 0.f};
    #pragma unroll
    for (int i = 0; i < 4; ++i)
        #pragma unroll
        for (int j = 0; j < 4; ++j) acc[i][j] = zero;

    // prefetch step 0 into buffer 0
    #pragma unroll
    for (int i = 0; i < 6; ++i) async16(src[i], dst0[i]);

    for (int s = 0; s < 32; ++s) {
        const int cur = s & 1;
        __syncthreads();   // drains own vmcnt: buf[cur] complete; prev compute on buf[cur^1] done
        if (s + 1 < 32) {
            #pragma unroll
            for (int i = 0; i < 6; ++i)
                async16(src[i] + (size_t)(s + 1) * 512, cur ? dst0[i] : dst1[i]);
        }
        const _Float16* Abuf = cur ? Ab1 : Ab0;
        const _Float16* Bbuf = cur ? Bb1 : Bb0;

        h8 Bf[2][4];
        #pragma unroll
        for (int tn = 0; tn < 4; ++tn) {
            const int tixn = (nq >> 4) + tn;
            Bf[0][tn] = *(const h8*)&Bbuf[tixn * 512 + lane * 8];
            Bf[1][tn] = *(const h8*)&Bbuf[(16 + tixn) * 512 + lane * 8];
        }
        #pragma unroll
        for (int tm = 0; tm < 4; ++tm) {
            const int tixm = (mq >> 4) + tm;
            const h8 Ah = *(const h8*)&Abuf[tixm * 512 + lane * 8];
            const h8 Al = *(const h8*)&Abuf[(8 + tixm) * 512 + lane * 8];
            #pragma unroll
            for (int tn = 0; tn < 4; ++tn) {
                acc[tm][tn] = __builtin_amdgcn_mfma_f32_16x16x32_f16(Ah, Bf[0][tn], acc[tm][tn], 0, 0, 0);
                acc[tm][tn] = __builtin_amdgcn_mfma_f32_16x16x32_f16(Ah, Bf[1][tn], acc[tm][tn], 0, 0, 0);
                acc[tm][tn] = __builtin_amdgcn_mfma_f32_16x16x32_f16(Al, Bf[0][tn], acc[tm][tn], 0, 0, 0);
            }
        }
    }

    // ---- epilogue: per-row argmin over this block's 256 cols ----
    float cnv[4];
    #pragma unroll
    for (int tn = 0; tn < 4; ++tn) cnv[tn] = cn[n0g + nq + tn * 16 + lo16];

    #pragma unroll
    for (int tm = 0; tm < 4; ++tm) {
        #pragma unroll
        for (int r = 0; r < 4; ++r) {
            float bv = FLT_MAX;
            int   bi = 0;
            #pragma unroll
            for (int tn = 0; tn < 4; ++tn) {   // ascending col => first-index tie-break
                const float v = cnv[tn] - acc[tm][tn][r] * DOT_UNSCALE_2;
                if (v < bv) { bv = v; bi = nq + tn * 16 + lo16; }
            }
            #pragma unroll
            for (int msk = 1; msk < 16; msk <<= 1) {
                const float ov = __shfl_xor(bv, msk, 64);
                const int   oi = __shfl_xor(bi, msk, 64);
                if (ov < bv || (ov == bv && oi < bi)) { bv = ov; bi = oi; }
            }
            if (lo16 == 0) {
                const int row = mq + tm * 16 + hi4 * 4 + r;
                const int g   = wave >> 1;     // n-quadrant index (ascending n)
                cV[row * 4 + g] = bv;
                cI[row * 4 + g] = bi;
            }
        }
    }
    __syncthreads();
    if (t < 128) {
        float bv = FLT_MAX;
        int   bi = 0;
        #pragma unroll
        for (int g = 0; g < 4; ++g) {          // ascending n-base, strict <
            const float v = cV[t * 4 + g];
            const int   i = cI[t * 4 + g];
            if (v < bv || (v == bv && i < bi)) { bv = v; bi = i; }
        }
        const int row = rt * 128 + t;
        pV[row * 4 + ct] = bv;
        pI[row * 4 + ct] = n0g + bi;
    }
}

// ---------------------------------------------------------------------------
// Final argmin across the 4 col-tiles (ascending, numpy tie-break).
// ---------------------------------------------------------------------------
__global__ __launch_bounds__(256) void reduce_kernel(const float* __restrict__ pV,
                                                     const int* __restrict__ pI,
                                                     float* __restrict__ disc) {
    const int rid = blockIdx.x * 256 + threadIdx.x;
    float bv = FLT_MAX;
    int   bi = 0;
    #pragma unroll
    for (int c = 0; c < 4; ++c) {
        const float v = pV[rid * 4 + c];
        const int   i = pI[rid * 4 + c];
        if (v < bv || (v == bv && i < bi)) { bv = v; bi = i; }
    }
    disc[rid] = (float)bi;
}

// ---------------------------------------------------------------------------
// finalize: one block per d. E row d staged in LDS (4 KB), gather via ds_read.
// q = x + (e - x); loss += 1.25*mean((x-e)^2). Fully coalesced x/q streams.
// ---------------------------------------------------------------------------
__global__ __launch_bounds__(256) void finalize_kernel(const float* __restrict__ x,
                                                       const float* __restrict__ E,
                                                       const float* __restrict__ discf,
                                                       float* __restrict__ out,
                                                       float* __restrict__ loss) {
    __shared__ float Erow[1024];
    const int t = threadIdx.x;
    const int d = blockIdx.x;
    *(float4*)&Erow[t * 4] = *(const float4*)(E + (size_t)d * K_ + t * 4);
    __syncthreads();

    const int bl = t >> 6;           // wave id -> b offset
    const int c4 = (t & 63) * 4;
    float lsum = 0.f;
    #pragma unroll 4
    for (int bg = 0; bg < 64; bg += 4) {
        const int b = bg + bl;
        const float4 id4 = *(const float4*)(discf + b * 256 + c4);
        const size_t xoff = ((size_t)(b * 1024 + d) << 8) + c4;
        const float4 xv = *(const float4*)(x + xoff);
        const float e0 = Erow[(int)id4.x];
        const float e1 = Erow[(int)id4.y];
        const float e2 = Erow[(int)id4.z];
        const float e3 = Erow[(int)id4.w];
        float4 qv;
        qv.x = xv.x + (e0 - xv.x);
        qv.y = xv.y + (e1 - xv.y);
        qv.z = xv.z + (e2 - xv.z);
        qv.w = xv.w + (e3 - xv.w);
        *(float4*)(out + xoff) = qv;
        const float d0 = xv.x - e0, d1 = xv.y - e1, d2 = xv.z - e2, d3 = xv.w - e3;
        lsum += fmaf(d0, d0, fmaf(d1, d1, fmaf(d2, d2, d3 * d3)));
    }

    #pragma unroll
    for (int off = 32; off > 0; off >>= 1)
        lsum += __shfl_down(lsum, off);
    __shared__ float wsum[4];
    if ((t & 63) == 0) wsum[t >> 6] = lsum;
    __syncthreads();
    if (t == 0) {
        const float s = (wsum[0] + wsum[1]) + (wsum[2] + wsum[3]);
        atomicAdd(loss, s * (1.25f / 16777216.0f));
    }
}

// ---------------------------------------------------------------------------
extern "C" void kernel_launch(void* const* d_in, const int* in_sizes, int n_in,
                              void* d_out, int out_size, void* d_ws, size_t ws_size,
                              hipStream_t stream) {
    (void)in_sizes; (void)n_in; (void)out_size; (void)ws_size;
    const float* x = (const float*)d_in[0];   // (64,32,32,256) f32
    const float* E = (const float*)d_in[1];   // (1024,1024)    f32
    float* out = (float*)d_out;
    float* ws  = (float*)d_ws;

    _Float16* Eh = (_Float16*)(ws + WS_EH);
    _Float16* El = (_Float16*)(ws + WS_EL);
    float* cn    = ws + WS_CN;
    float* pcn   = ws + WS_PCN;
    float* pV    = ws + WS_PV;
    int*   pI    = (int*)(ws + WS_PI);

    _Float16* Xh = (_Float16*)out;            // q-region scratch (overwritten by finalize)
    _Float16* Xl = (_Float16*)out + NX_;
    float* disc  = out + DISC_OFF;
    float* loss  = out + LOSS_OFF;

    // Allow 100 KB dynamic LDS (gfx950 WG limit is 160 KB; default cap may be 64 KB).
    hipFuncSetAttribute((const void*)gemm_argmin_kernel,
                        hipFuncAttributeMaxDynamicSharedMemorySize, 102400);

    split_kernel   <<<2176, 256, 0, stream>>>(x, E, Xh, Xl, Eh, El, pcn);
    colnorm2_kernel<<<16,   256, 0, stream>>>(pcn, cn, loss);
    gemm_argmin_kernel<<<512, 512, 102400, stream>>>(Xh, Xl, Eh, El, cn, pV, pI);
    reduce_kernel  <<<64,   256, 0, stream>>>(pV, pI, disc);
    finalize_kernel<<<1024, 256, 0, stream>>>(x, E, disc, out, loss);
}

// Round 6
// 246.508 us; speedup vs baseline: 1.0469x; 1.0469x over previous
//
#include <hip/hip_runtime.h>
#include <float.h>
#include <stdint.h>

// Problem constants: B=64, H=W=32, C=256, D=H*W=1024, K=1024
#define B_   64
#define C_   256
#define D_   1024
#define K_   1024
#define M_   16384
#define NX_  16777216          // B*D*C = M*D
#define DISC_OFF NX_
#define LOSS_OFF (NX_ + M_)

typedef _Float16 h8 __attribute__((ext_vector_type(8)));
typedef float    f4 __attribute__((ext_vector_type(4)));

// Power-of-2 split scales (exact). acc = 2^20 * dot.
#define XSCALE 512.0f
#define ESCALE 2048.0f
#define DOT_UNSCALE_2 (2.0f / 1048576.0f)

// d_ws layout (float offsets).
#define WS_EH  0          // 1M fp16 = 524288 floats
#define WS_EL  524288
#define WS_CN  1048576    // 1024
#define WS_PCN 1049600    // 128*1024 = 131072
#define WS_PV  1180672    // 16384*4 = 65536
#define WS_PI  1246208    // 16384*4 = 65536

__device__ __forceinline__ void async16(const _Float16* g, _Float16* l) {
    __builtin_amdgcn_global_load_lds(
        (const __attribute__((address_space(1))) unsigned int*)g,
        (__attribute__((address_space(3))) unsigned int*)l, 16, 0, 0);
}

// ---------------------------------------------------------------------------
// E split only (X split is now fused into the GEMM's A-staging path).
// 128 blocks: block = one k-octet o; thread = 4 consecutive n (16B loads).
// Produces fragment-tiled fp16 hi/lo planes + colnorm partials, bit-identical
// to all previous rounds.
// ---------------------------------------------------------------------------
__global__ __launch_bounds__(256) void esplit_kernel(const float* __restrict__ E,
                                                     _Float16* __restrict__ Eh,
                                                     _Float16* __restrict__ El,
                                                     float* __restrict__ pcn) {
    const int t  = threadIdx.x;
    const int o  = blockIdx.x;     // k-octet [0,128)
    const int d0 = o * 8;
    const int n0 = t * 4;          // 4 consecutive columns
    float4 row[8];
    #pragma unroll
    for (int i = 0; i < 8; ++i)
        row[i] = *(const float4*)(E + (size_t)(d0 + i) * K_ + n0);
    float s0 = 0.f, s1 = 0.f, s2 = 0.f, s3 = 0.f;
    h8 hh[4], ll[4];
    #pragma unroll
    for (int i = 0; i < 8; ++i) {
        const float* rp = (const float*)&row[i];
        #pragma unroll
        for (int j = 0; j < 4; ++j) {
            const float v  = rp[j];
            const float vs = v * ESCALE;
            const _Float16 h = (_Float16)vs;
            hh[j][i] = h;
            ll[j][i] = (_Float16)(vs - (float)h);
        }
        s0 = fmaf(rp[0], rp[0], s0);
        s1 = fmaf(rp[1], rp[1], s1);
        s2 = fmaf(rp[2], rp[2], s2);
        s3 = fmaf(rp[3], rp[3], s3);
    }
    float4 sv; sv.x = s0; sv.y = s1; sv.z = s2; sv.w = s3;
    *(float4*)(pcn + o * K_ + n0) = sv;
    const int nt    = n0 >> 4;
    const int kt    = o >> 2;
    const int lane0 = (n0 & 15) + (o & 3) * 16;
    const size_t base = ((size_t)(nt * 32 + kt) * 64 + lane0) * 8;
    #pragma unroll
    for (int j = 0; j < 4; ++j) {
        *(h8*)(Eh + base + (size_t)j * 8) = hh[j];
        *(h8*)(El + base + (size_t)j * 8) = ll[j];
    }
}

// colnorm: sum the 128 partials per column; zero the loss slot.
__global__ __launch_bounds__(256) void colnorm2_kernel(const float* __restrict__ pcn,
                                                       float* __restrict__ cn,
                                                       float* __restrict__ loss_slot) {
    __shared__ float sp[4][64];
    const int t    = threadIdx.x;
    const int col  = blockIdx.x * 64 + (t & 63);
    const int part = t >> 6;
    float s = 0.f;
    #pragma unroll 8
    for (int i = 0; i < 32; ++i) s += pcn[(part * 32 + i) * K_ + col];
    sp[part][t & 63] = s;
    __syncthreads();
    if (t < 64) cn[col] = (sp[0][t] + sp[1][t]) + (sp[2][t] + sp[3][t]);
    if (blockIdx.x == 0 && t == 0) *loss_slot = 0.0f;
}

// ---------------------------------------------------------------------------
// Split-fp16 MFMA distance GEMM + per-block argmin, with FUSED X split.
// R0's proven structure (128x256 tile, 512 thr, 8 waves, BK=32, dbuf LDS,
// one barrier/k-step, cross-step prefetch). A is no longer pre-split:
// each thread loads 8 f32 of x (one m-row, 8 consecutive k; coalesced
// 256B/instr across the wave), converts to fp16 hi/lo in regs, and
// ds_writes the fragment-tiled chunk into the NEXT LDS buffer after the
// MFMA phase (same values bit-for-bit as the old pre-split planes).
// B (E planes) still staged via global_load_lds (4 chunks/wave).
// Saves the 128 MB x-split kernel pass entirely; A LDS bytes unchanged.
// Grid 512 = 128 rt x 4 ct (consecutive blocks share rt -> A via L2/L3).
// ---------------------------------------------------------------------------
__global__ __launch_bounds__(512, 2) void gemm_argmin_kernel(
        const float* __restrict__ x,
        const _Float16* __restrict__ Eh, const _Float16* __restrict__ El,
        const float* __restrict__ cn,
        float* __restrict__ pV, int* __restrict__ pI) {
    extern __shared__ _Float16 smem[];
    // A buffers: [2][plane*8+mt][512]   (8192 fp16 each)
    // B buffers: [2][plane*16+nt][512]  (16384 fp16 each)
    _Float16* Ab0 = smem;
    _Float16* Ab1 = smem + 8192;
    _Float16* Bb0 = smem + 16384;
    _Float16* Bb1 = smem + 32768;
    float* cV = (float*)(smem + 49152);   // [128][4]
    int*   cI = (int*)(cV + 512);         // [128][4]

    const int t    = threadIdx.x;
    const int rt   = blockIdx.x >> 2;     // 0..127
    const int ct   = blockIdx.x & 3;      // 0..3
    const int wave = t >> 6, lane = t & 63;
    const int lo16 = lane & 15, hi4 = lane >> 4;
    const int mq   = (wave & 1) * 64;
    const int nq   = (wave >> 1) * 64;    // 0,64,128,192
    const int nt0  = ct * 16;
    const int n0g  = ct * 256;

    // ---- B staging: 32 async chunk-loads per k-step, 4 per wave ----
    const _Float16* srcB[4];
    _Float16* dstB0[4];
    _Float16* dstB1[4];
    #pragma unroll
    for (int i = 0; i < 4; ++i) {
        const int id = wave * 4 + i;          // 0..31
        const int plane = id >> 4, nt = id & 15;
        srcB[i]  = (plane ? El : Eh) + ((size_t)(nt0 + nt) * 32) * 512 + lane * 8;
        dstB0[i] = Bb0 + (plane * 16 + nt) * 512 + lane * 8;
        dstB1[i] = Bb1 + (plane * 16 + nt) * 512 + lane * 8;
    }

    // ---- A reg-staging geometry (fused x split) ----
    // tile rows m = rt*128 + cl, cl = t&127 (one b, 128 consecutive c).
    const int b    = rt >> 1;
    const int c0   = (rt & 1) * 128;
    const int cl   = t & 127;
    const int ko8  = t >> 7;              // k-octet within BK=32: 0..3
    const float* xbase = x + ((size_t)(b * 1024 + ko8 * 8)) * 256 + c0 + cl;
    const int mt    = cl >> 4;
    const int lane0 = (cl & 15) + ko8 * 16;
    _Float16* wA[2] = { Ab0 + mt * 512 + lane0 * 8,
                        Ab1 + mt * 512 + lane0 * 8 };   // lo plane at +4096

    float av[8];
    auto loadA = [&](int s) {
        #pragma unroll
        for (int j = 0; j < 8; ++j)
            av[j] = xbase[((size_t)(s * 32) + j) * 256];
    };
    auto writeA = [&](_Float16* w) {
        h8 hh, ll;
        #pragma unroll
        for (int j = 0; j < 8; ++j) {
            const float vs = av[j] * XSCALE;
            const _Float16 h = (_Float16)vs;
            hh[j] = h;
            ll[j] = (_Float16)(vs - (float)h);
        }
        *(h8*)w = hh;
        *(h8*)(w + 4096) = ll;
    };

    f4 acc[4][4];
    const f4 zero = {0.f, 0.f, 0.f, 0.f};
    #pragma unroll
    for (int i = 0; i < 4; ++i)
        #pragma unroll
        for (int j = 0; j < 4; ++j) acc[i][j] = zero;

    // prologue: stage step 0 into buffer 0 (B async + A reg->LDS)
    #pragma unroll
    for (int i = 0; i < 4; ++i) async16(srcB[i], dstB0[i]);
    loadA(0);
    writeA(wA[0]);

    for (int s = 0; s < 32; ++s) {
        const int cur = s & 1;
        __syncthreads();   // drains vmcnt+lgkm: buf[cur] complete; prev reads done
        if (s + 1 < 32) {
            #pragma unroll
            for (int i = 0; i < 4; ++i)
                async16(srcB[i] + (size_t)(s + 1) * 512, cur ? dstB0[i] : dstB1[i]);
            loadA(s + 1);                       // issued early, used after MFMA
        }
        const _Float16* Abuf = cur ? Ab1 : Ab0;
        const _Float16* Bbuf = cur ? Bb1 : Bb0;

        h8 Bf[2][4];
        #pragma unroll
        for (int tn = 0; tn < 4; ++tn) {
            const int tixn = (nq >> 4) + tn;
            Bf[0][tn] = *(const h8*)&Bbuf[tixn * 512 + lane * 8];
            Bf[1][tn] = *(const h8*)&Bbuf[(16 + tixn) * 512 + lane * 8];
        }
        #pragma unroll
        for (int tm = 0; tm < 4; ++tm) {
            const int tixm = (mq >> 4) + tm;
            const h8 Ah = *(const h8*)&Abuf[tixm * 512 + lane * 8];
            const h8 Al = *(const h8*)&Abuf[(8 + tixm) * 512 + lane * 8];
            #pragma unroll
            for (int tn = 0; tn < 4; ++tn) {
                acc[tm][tn] = __builtin_amdgcn_mfma_f32_16x16x32_f16(Ah, Bf[0][tn], acc[tm][tn], 0, 0, 0);
                acc[tm][tn] = __builtin_amdgcn_mfma_f32_16x16x32_f16(Ah, Bf[1][tn], acc[tm][tn], 0, 0, 0);
                acc[tm][tn] = __builtin_amdgcn_mfma_f32_16x16x32_f16(Al, Bf[0][tn], acc[tm][tn], 0, 0, 0);
            }
        }
        if (s + 1 < 32) writeA(cur ? wA[0] : wA[1]);   // into buf[cur^1]
    }

    // ---- epilogue: per-row argmin over this block's 256 cols ----
    float cnv[4];
    #pragma unroll
    for (int tn = 0; tn < 4; ++tn) cnv[tn] = cn[n0g + nq + tn * 16 + lo16];

    #pragma unroll
    for (int tm = 0; tm < 4; ++tm) {
        #pragma unroll
        for (int r = 0; r < 4; ++r) {
            float bv = FLT_MAX;
            int   bi = 0;
            #pragma unroll
            for (int tn = 0; tn < 4; ++tn) {   // ascending col => first-index tie-break
                const float v = cnv[tn] - acc[tm][tn][r] * DOT_UNSCALE_2;
                if (v < bv) { bv = v; bi = nq + tn * 16 + lo16; }
            }
            #pragma unroll
            for (int msk = 1; msk < 16; msk <<= 1) {
                const float ov = __shfl_xor(bv, msk, 64);
                const int   oi = __shfl_xor(bi, msk, 64);
                if (ov < bv || (ov == bv && oi < bi)) { bv = ov; bi = oi; }
            }
            if (lo16 == 0) {
                const int row = mq + tm * 16 + hi4 * 4 + r;
                const int g   = wave >> 1;     // n-quadrant index (ascending n)
                cV[row * 4 + g] = bv;
                cI[row * 4 + g] = bi;
            }
        }
    }
    __syncthreads();
    if (t < 128) {
        float bv = FLT_MAX;
        int   bi = 0;
        #pragma unroll
        for (int g = 0; g < 4; ++g) {          // ascending n-base, strict <
            const float v = cV[t * 4 + g];
            const int   i = cI[t * 4 + g];
            if (v < bv || (v == bv && i < bi)) { bv = v; bi = i; }
        }
        const int row = rt * 128 + t;
        pV[row * 4 + ct] = bv;
        pI[row * 4 + ct] = n0g + bi;
    }
}

// ---------------------------------------------------------------------------
// Final argmin across the 4 col-tiles (ascending, numpy tie-break).
// ---------------------------------------------------------------------------
__global__ __launch_bounds__(256) void reduce_kernel(const float* __restrict__ pV,
                                                     const int* __restrict__ pI,
                                                     float* __restrict__ disc) {
    const int rid = blockIdx.x * 256 + threadIdx.x;
    float bv = FLT_MAX;
    int   bi = 0;
    #pragma unroll
    for (int c = 0; c < 4; ++c) {
        const float v = pV[rid * 4 + c];
        const int   i = pI[rid * 4 + c];
        if (v < bv || (v == bv && i < bi)) { bv = v; bi = i; }
    }
    disc[rid] = (float)bi;
}

// ---------------------------------------------------------------------------
// finalize: one block per d. E row d staged in LDS (4 KB), gather via ds_read.
// q = x + (e - x); loss += 1.25*mean((x-e)^2). Fully coalesced x/q streams.
// ---------------------------------------------------------------------------
__global__ __launch_bounds__(256) void finalize_kernel(const float* __restrict__ x,
                                                       const float* __restrict__ E,
                                                       const float* __restrict__ discf,
                                                       float* __restrict__ out,
                                                       float* __restrict__ loss) {
    __shared__ float Erow[1024];
    const int t = threadIdx.x;
    const int d = blockIdx.x;
    *(float4*)&Erow[t * 4] = *(const float4*)(E + (size_t)d * K_ + t * 4);
    __syncthreads();

    const int bl = t >> 6;           // wave id -> b offset
    const int c4 = (t & 63) * 4;
    float lsum = 0.f;
    #pragma unroll 4
    for (int bg = 0; bg < 64; bg += 4) {
        const int b = bg + bl;
        const float4 id4 = *(const float4*)(discf + b * 256 + c4);
        const size_t xoff = ((size_t)(b * 1024 + d) << 8) + c4;
        const float4 xv = *(const float4*)(x + xoff);
        const float e0 = Erow[(int)id4.x];
        const float e1 = Erow[(int)id4.y];
        const float e2 = Erow[(int)id4.z];
        const float e3 = Erow[(int)id4.w];
        float4 qv;
        qv.x = xv.x + (e0 - xv.x);
        qv.y = xv.y + (e1 - xv.y);
        qv.z = xv.z + (e2 - xv.z);
        qv.w = xv.w + (e3 - xv.w);
        *(float4*)(out + xoff) = qv;
        const float d0 = xv.x - e0, d1 = xv.y - e1, d2 = xv.z - e2, d3 = xv.w - e3;
        lsum += fmaf(d0, d0, fmaf(d1, d1, fmaf(d2, d2, d3 * d3)));
    }

    #pragma unroll
    for (int off = 32; off > 0; off >>= 1)
        lsum += __shfl_down(lsum, off);
    __shared__ float wsum[4];
    if ((t & 63) == 0) wsum[t >> 6] = lsum;
    __syncthreads();
    if (t == 0) {
        const float s = (wsum[0] + wsum[1]) + (wsum[2] + wsum[3]);
        atomicAdd(loss, s * (1.25f / 16777216.0f));
    }
}

// ---------------------------------------------------------------------------
extern "C" void kernel_launch(void* const* d_in, const int* in_sizes, int n_in,
                              void* d_out, int out_size, void* d_ws, size_t ws_size,
                              hipStream_t stream) {
    (void)in_sizes; (void)n_in; (void)out_size; (void)ws_size;
    const float* x = (const float*)d_in[0];   // (64,32,32,256) f32
    const float* E = (const float*)d_in[1];   // (1024,1024)    f32
    float* out = (float*)d_out;
    float* ws  = (float*)d_ws;

    _Float16* Eh = (_Float16*)(ws + WS_EH);
    _Float16* El = (_Float16*)(ws + WS_EL);
    float* cn    = ws + WS_CN;
    float* pcn   = ws + WS_PCN;
    float* pV    = ws + WS_PV;
    int*   pI    = (int*)(ws + WS_PI);

    float* disc  = out + DISC_OFF;
    float* loss  = out + LOSS_OFF;

    // Allow 100 KB dynamic LDS (gfx950 WG limit is 160 KB; default cap may be 64 KB).
    hipFuncSetAttribute((const void*)gemm_argmin_kernel,
                        hipFuncAttributeMaxDynamicSharedMemorySize, 102400);

    esplit_kernel  <<<128,  256, 0, stream>>>(E, Eh, El, pcn);
    colnorm2_kernel<<<16,   256, 0, stream>>>(pcn, cn, loss);
    gemm_argmin_kernel<<<512, 512, 102400, stream>>>(x, Eh, El, cn, pV, pI);
    reduce_kernel  <<<64,   256, 0, stream>>>(pV, pI, disc);
    finalize_kernel<<<1024, 256, 0, stream>>>(x, E, disc, out, loss);
}

// Round 8
// 243.916 us; speedup vs baseline: 1.0580x; 1.0106x over previous
//
#include <hip/hip_runtime.h>
#include <float.h>
#include <stdint.h>

// Problem constants: B=64, H=W=32, C=256, D=H*W=1024, K=1024
#define B_   64
#define C_   256
#define D_   1024
#define K_   1024
#define M_   16384
#define NX_  16777216          // B*D*C = M*D
#define DISC_OFF NX_
#define LOSS_OFF (NX_ + M_)

typedef _Float16 h8 __attribute__((ext_vector_type(8)));
typedef float    f4 __attribute__((ext_vector_type(4)));

// Power-of-2 split scales (exact). acc = 2^20 * dot.
#define XSCALE 512.0f
#define ESCALE 2048.0f
#define DOT_UNSCALE_2 (2.0f / 1048576.0f)

// d_ws layout (float offsets).
#define WS_EH  0          // 1M fp16 = 524288 floats
#define WS_EL  524288
#define WS_CN  1048576    // 1024
#define WS_PCN 1049600    // 128*1024 = 131072
#define WS_PV  1180672    // 16384*4 = 65536
#define WS_PI  1246208    // 16384*4 = 65536

__device__ __forceinline__ void async16(const _Float16* g, _Float16* l) {
    __builtin_amdgcn_global_load_lds(
        (const __attribute__((address_space(1))) unsigned int*)g,
        (__attribute__((address_space(3))) unsigned int*)l, 16, 0, 0);
}
__device__ __forceinline__ void async16f(const float* g, float* l) {
    __builtin_amdgcn_global_load_lds(
        (const __attribute__((address_space(1))) unsigned int*)g,
        (__attribute__((address_space(3))) unsigned int*)l, 16, 0, 0);
}

// ---------------------------------------------------------------------------
// E split only (X split is fused into the GEMM's A-staging path).
// 128 blocks: block = one k-octet o; thread = 4 consecutive n (16B loads).
// ---------------------------------------------------------------------------
__global__ __launch_bounds__(256) void esplit_kernel(const float* __restrict__ E,
                                                     _Float16* __restrict__ Eh,
                                                     _Float16* __restrict__ El,
                                                     float* __restrict__ pcn) {
    const int t  = threadIdx.x;
    const int o  = blockIdx.x;     // k-octet [0,128)
    const int d0 = o * 8;
    const int n0 = t * 4;          // 4 consecutive columns
    float4 row[8];
    #pragma unroll
    for (int i = 0; i < 8; ++i)
        row[i] = *(const float4*)(E + (size_t)(d0 + i) * K_ + n0);
    float s0 = 0.f, s1 = 0.f, s2 = 0.f, s3 = 0.f;
    h8 hh[4], ll[4];
    #pragma unroll
    for (int i = 0; i < 8; ++i) {
        const float* rp = (const float*)&row[i];
        #pragma unroll
        for (int j = 0; j < 4; ++j) {
            const float v  = rp[j];
            const float vs = v * ESCALE;
            const _Float16 h = (_Float16)vs;
            hh[j][i] = h;
            ll[j][i] = (_Float16)(vs - (float)h);
        }
        s0 = fmaf(rp[0], rp[0], s0);
        s1 = fmaf(rp[1], rp[1], s1);
        s2 = fmaf(rp[2], rp[2], s2);
        s3 = fmaf(rp[3], rp[3], s3);
    }
    float4 sv; sv.x = s0; sv.y = s1; sv.z = s2; sv.w = s3;
    *(float4*)(pcn + o * K_ + n0) = sv;
    const int nt    = n0 >> 4;
    const int kt    = o >> 2;
    const int lane0 = (n0 & 15) + (o & 3) * 16;
    const size_t base = ((size_t)(nt * 32 + kt) * 64 + lane0) * 8;
    #pragma unroll
    for (int j = 0; j < 4; ++j) {
        *(h8*)(Eh + base + (size_t)j * 8) = hh[j];
        *(h8*)(El + base + (size_t)j * 8) = ll[j];
    }
}

// colnorm: sum the 128 partials per column; zero the loss slot.
__global__ __launch_bounds__(256) void colnorm2_kernel(const float* __restrict__ pcn,
                                                       float* __restrict__ cn,
                                                       float* __restrict__ loss_slot) {
    __shared__ float sp[4][64];
    const int t    = threadIdx.x;
    const int col  = blockIdx.x * 64 + (t & 63);
    const int part = t >> 6;
    float s = 0.f;
    #pragma unroll 8
    for (int i = 0; i < 32; ++i) s += pcn[(part * 32 + i) * K_ + col];
    sp[part][t & 63] = s;
    __syncthreads();
    if (t < 64) cn[col] = (sp[0][t] + sp[1][t]) + (sp[2][t] + sp[3][t]);
    if (blockIdx.x == 0 && t == 0) *loss_slot = 0.0f;
}

// ---------------------------------------------------------------------------
// Split-fp16 MFMA distance GEMM + per-block argmin, FUSED X split v2.
// R0's proven barrier structure. A is staged ASYNC as raw f32 via
// global_load_lds (2 chunks/wave/step, linear [d][c] dest), then converted
// one step ahead: 8x ds_read_b32 (stride 512B, conflict-free) -> hi/lo fp16
// -> 2x ds_write_b128 into the fragment-tiled FRAG buffer (bit-identical to
// the old pre-split planes). Per-thread VMEM/step = 6 async16, same as R0.
// LDS: B 2x32KB + FRAG 2x16KB + F32 2x16KB = 128 KB (1 block/CU, as R0).
// NOTE: LDS buffer pointers are computed per-use from smem + offset (never
// brace-initialized pointer arrays -> gfx950 static-initializer error).
// ---------------------------------------------------------------------------
__global__ __launch_bounds__(512, 2) void gemm_argmin_kernel(
        const float* __restrict__ x,
        const _Float16* __restrict__ Eh, const _Float16* __restrict__ El,
        const float* __restrict__ cn,
        float* __restrict__ pV, int* __restrict__ pI) {
    extern __shared__ _Float16 smem[];   // 65536 fp16 = 128 KB
    // layout (fp16 offsets): B0 @0, B1 @16384, FRAG0 @32768, FRAG1 @40960,
    //                        F32_0 @49152 (8192 f32h = 16KB), F32_1 @57344

    const int t    = threadIdx.x;
    const int rt   = blockIdx.x >> 2;     // 0..127
    const int ct   = blockIdx.x & 3;      // 0..3
    const int wave = t >> 6, lane = t & 63;
    const int lo16 = lane & 15, hi4 = lane >> 4;
    const int mq   = (wave & 1) * 64;
    const int nq   = (wave >> 1) * 64;    // 0,64,128,192
    const int nt0  = ct * 16;
    const int n0g  = ct * 256;

    // ---- B staging: 32 async chunk-loads per k-step, 4 per wave ----
    const _Float16* srcB[4];
    int offB[4];
    #pragma unroll
    for (int i = 0; i < 4; ++i) {
        const int id = wave * 4 + i;          // 0..31
        const int plane = id >> 4, nt = id & 15;
        srcB[i] = (plane ? El : Eh) + ((size_t)(nt0 + nt) * 32) * 512 + lane * 8;
        offB[i] = (plane * 16 + nt) * 512 + lane * 8;
    }
    auto stageB = [&](int s) {
        _Float16* bbuf = smem + (s & 1) * 16384;
        #pragma unroll
        for (int i = 0; i < 4; ++i)
            async16(srcB[i] + (size_t)s * 512, bbuf + offB[i]);
    };

    // ---- A async f32 staging: 16 chunks of 1KB per step, 2 per wave ----
    // F32 layout: [d 0..32)[c 0..128) f32, linear. chunk cid = 2 d-rows.
    const int b  = rt >> 1;
    const int c0 = (rt & 1) * 128;
    const float* xsrcA = x + ((size_t)(b * 1024 + (lane >> 5))) * 256 + c0 + (lane & 31) * 4;
    const int cidA0 = wave * 2;
    auto stageA = [&](int s) {
        float* f32buf = (float*)(smem + 49152 + (s & 1) * 8192);
        #pragma unroll
        for (int i = 0; i < 2; ++i) {
            const int cid = cidA0 + i;
            async16f(xsrcA + (size_t)(s * 32 + cid * 2) * 256, f32buf + cid * 256 + lane * 4);
        }
    };

    // ---- conversion geometry: thread owns (cl = m-row, ko8 = k-octet) ----
    const int ko8   = wave >> 1;                 // 0..3
    const int cl    = (wave & 1) * 64 + lane;    // 0..127
    const int mtl   = cl >> 4;                   // 0..7
    const int lane0 = (cl & 15) + ko8 * 16;
    const int fr    = ko8 * 8 * 128 + cl;        // F32 float offset base
    const int fw    = mtl * 512 + lane0 * 8;     // FRAG fp16 offset (hi); lo +4096
    auto convert = [&](int s) {
        const float* f32buf = (const float*)(smem + 49152 + (s & 1) * 8192);
        _Float16* fragbuf = smem + 32768 + (s & 1) * 8192;
        float cv[8];
        #pragma unroll
        for (int j = 0; j < 8; ++j) cv[j] = f32buf[fr + j * 128];
        h8 hh, ll;
        #pragma unroll
        for (int j = 0; j < 8; ++j) {
            const float vs = cv[j] * XSCALE;
            const _Float16 h = (_Float16)vs;
            hh[j] = h;
            ll[j] = (_Float16)(vs - (float)h);
        }
        *(h8*)(fragbuf + fw) = hh;
        *(h8*)(fragbuf + 4096 + fw) = ll;
    };

    f4 acc[4][4];
    const f4 zero = {0.f, 0.f, 0.f, 0.f};
    #pragma unroll
    for (int i = 0; i < 4; ++i)
        #pragma unroll
        for (int j = 0; j < 4; ++j) acc[i][j] = zero;

    // ---- prologue ----
    stageA(0);
    stageB(0);
    __syncthreads();                 // F32[0], B[0] landed
    convert(0);                      // FRAG[0] ready after next barrier
    stageA(1);                       // A(1) raw, consumed by convert at s=0

    for (int s = 0; s < 32; ++s) {
        __syncthreads();   // drains vmcnt (B(s), A-f32(s+1)) + lgkm (FRAG(s) writes)
        if (s + 2 < 32) stageA(s + 2);
        if (s + 1 < 32) stageB(s + 1);
        if (s + 1 < 32) convert(s + 1);

        const _Float16* Abuf = smem + 32768 + (s & 1) * 8192;
        const _Float16* Bbuf = smem + (s & 1) * 16384;
        h8 Bf[2][4];
        #pragma unroll
        for (int tn = 0; tn < 4; ++tn) {
            const int tixn = (nq >> 4) + tn;
            Bf[0][tn] = *(const h8*)&Bbuf[tixn * 512 + lane * 8];
            Bf[1][tn] = *(const h8*)&Bbuf[(16 + tixn) * 512 + lane * 8];
        }
        #pragma unroll
        for (int tm = 0; tm < 4; ++tm) {
            const int tixm = (mq >> 4) + tm;
            const h8 Ah = *(const h8*)&Abuf[tixm * 512 + lane * 8];
            const h8 Al = *(const h8*)&Abuf[4096 + tixm * 512 + lane * 8];
            #pragma unroll
            for (int tn = 0; tn < 4; ++tn) {
                acc[tm][tn] = __builtin_amdgcn_mfma_f32_16x16x32_f16(Ah, Bf[0][tn], acc[tm][tn], 0, 0, 0);
                acc[tm][tn] = __builtin_amdgcn_mfma_f32_16x16x32_f16(Ah, Bf[1][tn], acc[tm][tn], 0, 0, 0);
                acc[tm][tn] = __builtin_amdgcn_mfma_f32_16x16x32_f16(Al, Bf[0][tn], acc[tm][tn], 0, 0, 0);
            }
        }
    }

    // ---- epilogue: per-row argmin over this block's 256 cols ----
    __syncthreads();
    float* cV = (float*)(smem + 49152);   // [128][4] (F32 region, now free)
    int*   cI = (int*)(cV + 512);         // [128][4]

    float cnv[4];
    #pragma unroll
    for (int tn = 0; tn < 4; ++tn) cnv[tn] = cn[n0g + nq + tn * 16 + lo16];

    #pragma unroll
    for (int tm = 0; tm < 4; ++tm) {
        #pragma unroll
        for (int r = 0; r < 4; ++r) {
            float bv = FLT_MAX;
            int   bi = 0;
            #pragma unroll
            for (int tn = 0; tn < 4; ++tn) {   // ascending col => first-index tie-break
                const float v = cnv[tn] - acc[tm][tn][r] * DOT_UNSCALE_2;
                if (v < bv) { bv = v; bi = nq + tn * 16 + lo16; }
            }
            #pragma unroll
            for (int msk = 1; msk < 16; msk <<= 1) {
                const float ov = __shfl_xor(bv, msk, 64);
                const int   oi = __shfl_xor(bi, msk, 64);
                if (ov < bv || (ov == bv && oi < bi)) { bv = ov; bi = oi; }
            }
            if (lo16 == 0) {
                const int row = mq + tm * 16 + hi4 * 4 + r;
                const int g   = wave >> 1;     // n-quadrant index (ascending n)
                cV[row * 4 + g] = bv;
                cI[row * 4 + g] = bi;
            }
        }
    }
    __syncthreads();
    if (t < 128) {
        float bv = FLT_MAX;
        int   bi = 0;
        #pragma unroll
        for (int g = 0; g < 4; ++g) {          // ascending n-base, strict <
            const float v = cV[t * 4 + g];
            const int   i = cI[t * 4 + g];
            if (v < bv || (v == bv && i < bi)) { bv = v; bi = i; }
        }
        const int row = rt * 128 + t;
        pV[row * 4 + ct] = bv;
        pI[row * 4 + ct] = n0g + bi;
    }
}

// ---------------------------------------------------------------------------
// Final argmin across the 4 col-tiles (ascending, numpy tie-break).
// ---------------------------------------------------------------------------
__global__ __launch_bounds__(256) void reduce_kernel(const float* __restrict__ pV,
                                                     const int* __restrict__ pI,
                                                     float* __restrict__ disc) {
    const int rid = blockIdx.x * 256 + threadIdx.x;
    float bv = FLT_MAX;
    int   bi = 0;
    #pragma unroll
    for (int c = 0; c < 4; ++c) {
        const float v = pV[rid * 4 + c];
        const int   i = pI[rid * 4 + c];
        if (v < bv || (v == bv && i < bi)) { bv = v; bi = i; }
    }
    disc[rid] = (float)bi;
}

// ---------------------------------------------------------------------------
// finalize: one block per d. E row d staged in LDS (4 KB), gather via ds_read.
// q = x + (e - x); loss += 1.25*mean((x-e)^2). Fully coalesced x/q streams.
// ---------------------------------------------------------------------------
__global__ __launch_bounds__(256) void finalize_kernel(const float* __restrict__ x,
                                                       const float* __restrict__ E,
                                                       const float* __restrict__ discf,
                                                       float* __restrict__ out,
                                                       float* __restrict__ loss) {
    __shared__ float Erow[1024];
    const int t = threadIdx.x;
    const int d = blockIdx.x;
    *(float4*)&Erow[t * 4] = *(const float4*)(E + (size_t)d * K_ + t * 4);
    __syncthreads();

    const int bl = t >> 6;           // wave id -> b offset
    const int c4 = (t & 63) * 4;
    float lsum = 0.f;
    #pragma unroll 4
    for (int bg = 0; bg < 64; bg += 4) {
        const int b = bg + bl;
        const float4 id4 = *(const float4*)(discf + b * 256 + c4);
        const size_t xoff = ((size_t)(b * 1024 + d) << 8) + c4;
        const float4 xv = *(const float4*)(x + xoff);
        const float e0 = Erow[(int)id4.x];
        const float e1 = Erow[(int)id4.y];
        const float e2 = Erow[(int)id4.z];
        const float e3 = Erow[(int)id4.w];
        float4 qv;
        qv.x = xv.x + (e0 - xv.x);
        qv.y = xv.y + (e1 - xv.y);
        qv.z = xv.z + (e2 - xv.z);
        qv.w = xv.w + (e3 - xv.w);
        *(float4*)(out + xoff) = qv;
        const float d0 = xv.x - e0, d1 = xv.y - e1, d2 = xv.z - e2, d3 = xv.w - e3;
        lsum += fmaf(d0, d0, fmaf(d1, d1, fmaf(d2, d2, d3 * d3)));
    }

    #pragma unroll
    for (int off = 32; off > 0; off >>= 1)
        lsum += __shfl_down(lsum, off);
    __shared__ float wsum[4];
    if ((t & 63) == 0) wsum[t >> 6] = lsum;
    __syncthreads();
    if (t == 0) {
        const float s = (wsum[0] + wsum[1]) + (wsum[2] + wsum[3]);
        atomicAdd(loss, s * (1.25f / 16777216.0f));
    }
}

// ---------------------------------------------------------------------------
extern "C" void kernel_launch(void* const* d_in, const int* in_sizes, int n_in,
                              void* d_out, int out_size, void* d_ws, size_t ws_size,
                              hipStream_t stream) {
    (void)in_sizes; (void)n_in; (void)out_size; (void)ws_size;
    const float* x = (const float*)d_in[0];   // (64,32,32,256) f32
    const float* E = (const float*)d_in[1];   // (1024,1024)    f32
    float* out = (float*)d_out;
    float* ws  = (float*)d_ws;

    _Float16* Eh = (_Float16*)(ws + WS_EH);
    _Float16* El = (_Float16*)(ws + WS_EL);
    float* cn    = ws + WS_CN;
    float* pcn   = ws + WS_PCN;
    float* pV    = ws + WS_PV;
    int*   pI    = (int*)(ws + WS_PI);

    float* disc  = out + DISC_OFF;
    float* loss  = out + LOSS_OFF;

    // Allow 128 KB dynamic LDS (default cap is 64 KB; gfx950 WG limit 160 KB).
    (void)hipFuncSetAttribute((const void*)gemm_argmin_kernel,
                              hipFuncAttributeMaxDynamicSharedMemorySize, 131072);

    esplit_kernel  <<<128,  256, 0, stream>>>(E, Eh, El, pcn);
    colnorm2_kernel<<<16,   256, 0, stream>>>(pcn, cn, loss);
    gemm_argmin_kernel<<<512, 512, 131072, stream>>>(x, Eh, El, cn, pV, pI);
    reduce_kernel  <<<64,   256, 0, stream>>>(pV, pI, disc);
    finalize_kernel<<<1024, 256, 0, stream>>>(x, E, disc, out, loss);
}

// Round 9
// 232.597 us; speedup vs baseline: 1.1095x; 1.0487x over previous
//
#include <hip/hip_runtime.h>
#include <float.h>
#include <stdint.h>

// Problem constants: B=64, H=W=32, C=256, D=H*W=1024, K=1024
#define B_   64
#define C_   256
#define D_   1024
#define K_   1024
#define M_   16384
#define NX_  16777216          // B*D*C = M*D
#define DISC_OFF NX_
#define LOSS_OFF (NX_ + M_)

typedef _Float16 h8 __attribute__((ext_vector_type(8)));
typedef float    f4 __attribute__((ext_vector_type(4)));

// Power-of-2 split scales (exact). acc = 2^20 * dot.
#define XSCALE 512.0f
#define ESCALE 2048.0f
#define DOT_UNSCALE_2 (2.0f / 1048576.0f)

// d_ws layout (float offsets).
#define WS_EH  0          // 1M fp16 = 524288 floats
#define WS_EL  524288
#define WS_CN  1048576    // 1024
#define WS_PCN 1049600    // 128*1024 = 131072
#define WS_PV  1180672    // 16384*4 = 65536
#define WS_PI  1246208    // 16384*4 = 65536

__device__ __forceinline__ void async16(const _Float16* g, _Float16* l) {
    __builtin_amdgcn_global_load_lds(
        (const __attribute__((address_space(1))) unsigned int*)g,
        (__attribute__((address_space(3))) unsigned int*)l, 16, 0, 0);
}

// ---------------------------------------------------------------------------
// E split only (X split is fused into the GEMM's A-staging path).
// 128 blocks: block = one k-octet o; thread = 4 consecutive n (16B loads).
// ---------------------------------------------------------------------------
__global__ __launch_bounds__(256) void esplit_kernel(const float* __restrict__ E,
                                                     _Float16* __restrict__ Eh,
                                                     _Float16* __restrict__ El,
                                                     float* __restrict__ pcn) {
    const int t  = threadIdx.x;
    const int o  = blockIdx.x;     // k-octet [0,128)
    const int d0 = o * 8;
    const int n0 = t * 4;          // 4 consecutive columns
    float4 row[8];
    #pragma unroll
    for (int i = 0; i < 8; ++i)
        row[i] = *(const float4*)(E + (size_t)(d0 + i) * K_ + n0);
    float s0 = 0.f, s1 = 0.f, s2 = 0.f, s3 = 0.f;
    h8 hh[4], ll[4];
    #pragma unroll
    for (int i = 0; i < 8; ++i) {
        const float* rp = (const float*)&row[i];
        #pragma unroll
        for (int j = 0; j < 4; ++j) {
            const float v  = rp[j];
            const float vs = v * ESCALE;
            const _Float16 h = (_Float16)vs;
            hh[j][i] = h;
            ll[j][i] = (_Float16)(vs - (float)h);
        }
        s0 = fmaf(rp[0], rp[0], s0);
        s1 = fmaf(rp[1], rp[1], s1);
        s2 = fmaf(rp[2], rp[2], s2);
        s3 = fmaf(rp[3], rp[3], s3);
    }
    float4 sv; sv.x = s0; sv.y = s1; sv.z = s2; sv.w = s3;
    *(float4*)(pcn + o * K_ + n0) = sv;
    const int nt    = n0 >> 4;
    const int kt    = o >> 2;
    const int lane0 = (n0 & 15) + (o & 3) * 16;
    const size_t base = ((size_t)(nt * 32 + kt) * 64 + lane0) * 8;
    #pragma unroll
    for (int j = 0; j < 4; ++j) {
        *(h8*)(Eh + base + (size_t)j * 8) = hh[j];
        *(h8*)(El + base + (size_t)j * 8) = ll[j];
    }
}

// colnorm: sum the 128 partials per column; zero the loss slot.
__global__ __launch_bounds__(256) void colnorm2_kernel(const float* __restrict__ pcn,
                                                       float* __restrict__ cn,
                                                       float* __restrict__ loss_slot) {
    __shared__ float sp[4][64];
    const int t    = threadIdx.x;
    const int col  = blockIdx.x * 64 + (t & 63);
    const int part = t >> 6;
    float s = 0.f;
    #pragma unroll 8
    for (int i = 0; i < 32; ++i) s += pcn[(part * 32 + i) * K_ + col];
    sp[part][t & 63] = s;
    __syncthreads();
    if (t < 64) cn[col] = (sp[0][t] + sp[1][t]) + (sp[2][t] + sp[3][t]);
    if (blockIdx.x == 0 && t == 0) *loss_slot = 0.0f;
}

// ---------------------------------------------------------------------------
// Split-fp16 MFMA distance GEMM + per-block argmin, FUSED X split v3.
// R0's proven barrier structure + reg-staged A conversion with a TWO-STEP
// pipeline lead (fixes R6's exposed load latency):
//   at step s: [barrier] -> stageB(s+1) async -> ds_write av (data s+1) into
//   FRAG[(s+1)&1] -> issue 8 scalar x-loads for step s+2 into av ->
//   sched_barrier(0) [pins load issue before the MFMA cluster] -> ds_read
//   frags -> 48 MFMA. The av loads issued at step s are consumed at step
//   s+1's ds_write: >= 1 full step (~3700 cyc) of cover >> 900 cyc HBM.
// Values bit-identical to the pre-split planes (same convert ops).
// LDS: B 2x32KB + FRAG 2x16KB + 4KB epilogue = 100 KB (1 block/CU, as R0).
// Grid 512 = 128 rt x 4 ct (consecutive blocks share rt -> A via L2/L3).
// ---------------------------------------------------------------------------
__global__ __launch_bounds__(512, 2) void gemm_argmin_kernel(
        const float* __restrict__ x,
        const _Float16* __restrict__ Eh, const _Float16* __restrict__ El,
        const float* __restrict__ cn,
        float* __restrict__ pV, int* __restrict__ pI) {
    extern __shared__ _Float16 smem[];   // 51200 fp16 = 100 KB
    // layout (fp16 offsets): B0 @0, B1 @16384, FRAG0 @32768 (hi 4096|lo 4096),
    //                        FRAG1 @40960, cV/cI @49152 (4 KB)

    const int t    = threadIdx.x;
    const int rt   = blockIdx.x >> 2;     // 0..127
    const int ct   = blockIdx.x & 3;      // 0..3
    const int wave = t >> 6, lane = t & 63;
    const int lo16 = lane & 15, hi4 = lane >> 4;
    const int mq   = (wave & 1) * 64;
    const int nq   = (wave >> 1) * 64;    // 0,64,128,192
    const int nt0  = ct * 16;
    const int n0g  = ct * 256;

    // ---- B staging: 32 async chunk-loads per k-step, 4 per wave ----
    const _Float16* srcB[4];
    int offB[4];
    #pragma unroll
    for (int i = 0; i < 4; ++i) {
        const int id = wave * 4 + i;          // 0..31
        const int plane = id >> 4, nt = id & 15;
        srcB[i] = (plane ? El : Eh) + ((size_t)(nt0 + nt) * 32) * 512 + lane * 8;
        offB[i] = (plane * 16 + nt) * 512 + lane * 8;
    }
    auto stageB = [&](int s) {
        _Float16* bbuf = smem + (s & 1) * 16384;
        #pragma unroll
        for (int i = 0; i < 4; ++i)
            async16(srcB[i] + (size_t)s * 512, bbuf + offB[i]);
    };

    // ---- A reg-staged fused split: thread owns (row cl, k-octet ko8) ----
    const int b   = rt >> 1;
    const int c0  = (rt & 1) * 128;
    const int cl  = t & 127;              // m-row within tile
    const int ko8 = t >> 7;               // local k-octet 0..3
    const float* xA = x + ((size_t)(b * 1024 + ko8 * 8)) * 256 + c0 + cl;
    const int fwr = (cl >> 4) * 512 + ((cl & 15) + ko8 * 16) * 8;

    float av[8];
    auto loadA = [&](int s) {             // data for step s -> av
        #pragma unroll
        for (int j = 0; j < 8; ++j)
            av[j] = xA[((size_t)(s * 32) + j) * 256];
    };
    auto writeA = [&](int s) {            // av -> FRAG[s&1] (bit-exact split)
        _Float16* fb = smem + 32768 + (s & 1) * 8192;
        h8 hh, ll;
        #pragma unroll
        for (int j = 0; j < 8; ++j) {
            const float vs = av[j] * XSCALE;
            const _Float16 h = (_Float16)vs;
            hh[j] = h;
            ll[j] = (_Float16)(vs - (float)h);
        }
        *(h8*)(fb + fwr) = hh;
        *(h8*)(fb + 4096 + fwr) = ll;
    };

    f4 acc[4][4];
    const f4 zero = {0.f, 0.f, 0.f, 0.f};
    #pragma unroll
    for (int i = 0; i < 4; ++i)
        #pragma unroll
        for (int j = 0; j < 4; ++j) acc[i][j] = zero;

    // ---- prologue: FRAG0 written, av holds step-1 data, B0 in flight ----
    loadA(0);
    writeA(0);
    loadA(1);
    stageB(0);

    for (int s = 0; s < 32; ++s) {
        __syncthreads();   // drains vmcnt (B(s)) + lgkm (FRAG(s) writes); barrier
        if (s + 1 < 32) {
            stageB(s + 1);
            writeA(s + 1);                 // av = data(s+1); vmcnt auto-wait
        }
        if (s + 2 < 32) loadA(s + 2);      // issued now, consumed next step
        __builtin_amdgcn_sched_barrier(0); // pin load issue before MFMA cluster

        const _Float16* Abuf = smem + 32768 + (s & 1) * 8192;
        const _Float16* Bbuf = smem + (s & 1) * 16384;
        h8 Bf[2][4];
        #pragma unroll
        for (int tn = 0; tn < 4; ++tn) {
            const int tixn = (nq >> 4) + tn;
            Bf[0][tn] = *(const h8*)&Bbuf[tixn * 512 + lane * 8];
            Bf[1][tn] = *(const h8*)&Bbuf[(16 + tixn) * 512 + lane * 8];
        }
        #pragma unroll
        for (int tm = 0; tm < 4; ++tm) {
            const int tixm = (mq >> 4) + tm;
            const h8 Ah = *(const h8*)&Abuf[tixm * 512 + lane * 8];
            const h8 Al = *(const h8*)&Abuf[4096 + tixm * 512 + lane * 8];
            #pragma unroll
            for (int tn = 0; tn < 4; ++tn) {
                acc[tm][tn] = __builtin_amdgcn_mfma_f32_16x16x32_f16(Ah, Bf[0][tn], acc[tm][tn], 0, 0, 0);
                acc[tm][tn] = __builtin_amdgcn_mfma_f32_16x16x32_f16(Ah, Bf[1][tn], acc[tm][tn], 0, 0, 0);
                acc[tm][tn] = __builtin_amdgcn_mfma_f32_16x16x32_f16(Al, Bf[0][tn], acc[tm][tn], 0, 0, 0);
            }
        }
    }

    // ---- epilogue: per-row argmin over this block's 256 cols ----
    __syncthreads();
    float* cV = (float*)(smem + 49152);   // [128][4]
    int*   cI = (int*)(cV + 512);         // [128][4]

    float cnv[4];
    #pragma unroll
    for (int tn = 0; tn < 4; ++tn) cnv[tn] = cn[n0g + nq + tn * 16 + lo16];

    #pragma unroll
    for (int tm = 0; tm < 4; ++tm) {
        #pragma unroll
        for (int r = 0; r < 4; ++r) {
            float bv = FLT_MAX;
            int   bi = 0;
            #pragma unroll
            for (int tn = 0; tn < 4; ++tn) {   // ascending col => first-index tie-break
                const float v = cnv[tn] - acc[tm][tn][r] * DOT_UNSCALE_2;
                if (v < bv) { bv = v; bi = nq + tn * 16 + lo16; }
            }
            #pragma unroll
            for (int msk = 1; msk < 16; msk <<= 1) {
                const float ov = __shfl_xor(bv, msk, 64);
                const int   oi = __shfl_xor(bi, msk, 64);
                if (ov < bv || (ov == bv && oi < bi)) { bv = ov; bi = oi; }
            }
            if (lo16 == 0) {
                const int row = mq + tm * 16 + hi4 * 4 + r;
                const int g   = wave >> 1;     // n-quadrant index (ascending n)
                cV[row * 4 + g] = bv;
                cI[row * 4 + g] = bi;
            }
        }
    }
    __syncthreads();
    if (t < 128) {
        float bv = FLT_MAX;
        int   bi = 0;
        #pragma unroll
        for (int g = 0; g < 4; ++g) {          // ascending n-base, strict <
            const float v = cV[t * 4 + g];
            const int   i = cI[t * 4 + g];
            if (v < bv || (v == bv && i < bi)) { bv = v; bi = i; }
        }
        const int row = rt * 128 + t;
        pV[row * 4 + ct] = bv;
        pI[row * 4 + ct] = n0g + bi;
    }
}

// ---------------------------------------------------------------------------
// Final argmin across the 4 col-tiles (ascending, numpy tie-break).
// ---------------------------------------------------------------------------
__global__ __launch_bounds__(256) void reduce_kernel(const float* __restrict__ pV,
                                                     const int* __restrict__ pI,
                                                     float* __restrict__ disc) {
    const int rid = blockIdx.x * 256 + threadIdx.x;
    float bv = FLT_MAX;
    int   bi = 0;
    #pragma unroll
    for (int c = 0; c < 4; ++c) {
        const float v = pV[rid * 4 + c];
        const int   i = pI[rid * 4 + c];
        if (v < bv || (v == bv && i < bi)) { bv = v; bi = i; }
    }
    disc[rid] = (float)bi;
}

// ---------------------------------------------------------------------------
// finalize: one block per d. E row d staged in LDS (4 KB), gather via ds_read.
// q = x + (e - x); loss += 1.25*mean((x-e)^2). Fully coalesced x/q streams.
// ---------------------------------------------------------------------------
__global__ __launch_bounds__(256) void finalize_kernel(const float* __restrict__ x,
                                                       const float* __restrict__ E,
                                                       const float* __restrict__ discf,
                                                       float* __restrict__ out,
                                                       float* __restrict__ loss) {
    __shared__ float Erow[1024];
    const int t = threadIdx.x;
    const int d = blockIdx.x;
    *(float4*)&Erow[t * 4] = *(const float4*)(E + (size_t)d * K_ + t * 4);
    __syncthreads();

    const int bl = t >> 6;           // wave id -> b offset
    const int c4 = (t & 63) * 4;
    float lsum = 0.f;
    #pragma unroll 4
    for (int bg = 0; bg < 64; bg += 4) {
        const int b = bg + bl;
        const float4 id4 = *(const float4*)(discf + b * 256 + c4);
        const size_t xoff = ((size_t)(b * 1024 + d) << 8) + c4;
        const float4 xv = *(const float4*)(x + xoff);
        const float e0 = Erow[(int)id4.x];
        const float e1 = Erow[(int)id4.y];
        const float e2 = Erow[(int)id4.z];
        const float e3 = Erow[(int)id4.w];
        float4 qv;
        qv.x = xv.x + (e0 - xv.x);
        qv.y = xv.y + (e1 - xv.y);
        qv.z = xv.z + (e2 - xv.z);
        qv.w = xv.w + (e3 - xv.w);
        *(float4*)(out + xoff) = qv;
        const float d0 = xv.x - e0, d1 = xv.y - e1, d2 = xv.z - e2, d3 = xv.w - e3;
        lsum += fmaf(d0, d0, fmaf(d1, d1, fmaf(d2, d2, d3 * d3)));
    }

    #pragma unroll
    for (int off = 32; off > 0; off >>= 1)
        lsum += __shfl_down(lsum, off);
    __shared__ float wsum[4];
    if ((t & 63) == 0) wsum[t >> 6] = lsum;
    __syncthreads();
    if (t == 0) {
        const float s = (wsum[0] + wsum[1]) + (wsum[2] + wsum[3]);
        atomicAdd(loss, s * (1.25f / 16777216.0f));
    }
}

// ---------------------------------------------------------------------------
extern "C" void kernel_launch(void* const* d_in, const int* in_sizes, int n_in,
                              void* d_out, int out_size, void* d_ws, size_t ws_size,
                              hipStream_t stream) {
    (void)in_sizes; (void)n_in; (void)out_size; (void)ws_size;
    const float* x = (const float*)d_in[0];   // (64,32,32,256) f32
    const float* E = (const float*)d_in[1];   // (1024,1024)    f32
    float* out = (float*)d_out;
    float* ws  = (float*)d_ws;

    _Float16* Eh = (_Float16*)(ws + WS_EH);
    _Float16* El = (_Float16*)(ws + WS_EL);
    float* cn    = ws + WS_CN;
    float* pcn   = ws + WS_PCN;
    float* pV    = ws + WS_PV;
    int*   pI    = (int*)(ws + WS_PI);

    float* disc  = out + DISC_OFF;
    float* loss  = out + LOSS_OFF;

    // Allow 100 KB dynamic LDS (default cap is 64 KB; gfx950 WG limit 160 KB).
    (void)hipFuncSetAttribute((const void*)gemm_argmin_kernel,
                              hipFuncAttributeMaxDynamicSharedMemorySize, 102400);

    esplit_kernel  <<<128,  256, 0, stream>>>(E, Eh, El, pcn);
    colnorm2_kernel<<<16,   256, 0, stream>>>(pcn, cn, loss);
    gemm_argmin_kernel<<<512, 512, 102400, stream>>>(x, Eh, El, cn, pV, pI);
    reduce_kernel  <<<64,   256, 0, stream>>>(pV, pI, disc);
    finalize_kernel<<<1024, 256, 0, stream>>>(x, E, disc, out, loss);
}